// Round 15
// baseline (224.557 us; speedup 1.0000x reference)
//
#include <hip/hip_runtime.h>
#include <hip/hip_bf16.h>
#include <hip/hip_fp16.h>

#define NTGT 2048
#define NSRC 4096
#define NPATCH 32
#define NY 48
#define PITCH 136          // 136 mod 16 == 8 -> s-streams hit disjoint bank windows
#define NCG2 3524          // padded z-major cg table (halves)
#define NSLOTS 1280        // 20 rounds x 64
#define DESC_OFF 16384     // byte offset of descriptor table in d_ws
#define KBF_OFF 32768      // byte offset of transposed bf16 kern in d_ws
#define KBF_ELEMS ((size_t)4096 * NY * NPATCH)   // 6.29M bf16 = 12.58 MB

using short8 = __attribute__((ext_vector_type(8))) short;
using f32x4  = __attribute__((ext_vector_type(4))) float;

#define NTERMS 34
// term tables: order matches reference out[J] concatenation order (r2-proven)
__constant__ int T_j[NTERMS]    = {0,1,2,3, 1,0,1,2,1,2,3,2,3, 2,0,1,2,3,1,2,3,1,2,3, 3,0,2,3,1,2,3,1,2,3};
__constant__ int T_l[NTERMS]    = {0,1,2,3, 0,1,1,1,2,2,2,3,3, 0,2,1,1,1,2,2,2,3,3,3, 0,3,1,1,2,2,2,3,3,3};
__constant__ int T_Jv[NTERMS]   = {0,0,0,0, 1,1,1,1,1,1,1,1,1, 2,2,2,2,2,2,2,2,2,2,2, 3,3,3,3,3,3,3,3,3,3};
__constant__ int T_col[NTERMS]  = {0,1,2,3, 0,1,2,3,4,5,6,7,8, 0,1,2,3,4,5,6,7,8,9,10, 0,1,2,3,4,5,6,7,8,9};
__constant__ int OUT_BASE[4] = {0, 1572864, 12189696, 33816576};
__constant__ int OUT_W[4]    = {384, 864, 1056, 960};
__constant__ int NJW_C[4]    = {384, 2592, 5280, 6720};   // (2J+1)*W
// n-tile li -> (l, ml, row-width/32) for phase-1 B gather
__constant__ int LI_L[16]  = {0,1,1,1,2,2,2,2,2,3,3,3,3,3,3,3};
__constant__ int LI_ML[16] = {0,0,1,2,0,1,2,3,4,0,1,2,3,4,5,6};
__constant__ int LI_WQ[16] = {1,3,3,3,5,5,5,5,5,7,7,7,7,7,7,7};
// phase-2 schedule: desc slot base per term (class-pure 64-slot rounds)
__constant__ int TERM_SLOT[NTERMS] = {1088,1024,384,0, 1094,1184,1030,896,768,390,256,128,6,
                                      1112,1202,1048,914,640,786,408,274,512,146,24,
                                      1142,1232,944,670,816,438,304,542,176,54};
// cg2 base offset (float4-unit indexing) per term (0 for copy terms)
__constant__ int CG2OFF4[NTERMS] = {0,0,3,10, 0,0,23,32,44,56,77,104,131,
                                    0,0,170,185,205,235,255,290,335,365,410,
                                    0,0,475,503,545,573,622,685,727,790};
// round -> class: 0:(3,3) 1:(2,3) 2:(3,2) 3:(2,2) 4:(1,3) 5:(3,1) 6:(1,2) 7:(2,1) 8:(1,1) 9:copy
__constant__ int RND_CLASS[20] = {0,0,1,1,2,2,3,3,4,4,5,5,6,6,7,7,8,9,9,9};
// wave -> its rounds (balanced: max 58 iter-units vs avg 56)
__constant__ signed char WAVE_RNDS[8][3] = {
  {0,17,-1},{1,16,-1},{2,8,-1},{3,9,18},{4,10,19},{5,11,-1},{6,14,13},{7,15,12}};

// ---------------- CG math (device, double precision) ----------------
__device__ double factd(int n) { double r = 1.0; for (int i = 2; i <= n; ++i) r *= i; return r; }

__device__ double su2_cg(int j1, int m1, int j2, int m2, int j3, int m3) {
  if (m3 != m1 + m2) return 0.0;
  int vmin = max(max(-j1 + j2 + m3, -j1 + m1), 0);
  int vmax = min(min(j2 + j3 + m1, j3 - j1 + j2), j3 + m3);
  double cc = sqrt((2.0*j3 + 1.0) * factd(j3 + j1 - j2) * factd(j3 - j1 + j2) * factd(j1 + j2 - j3)
                   / factd(j1 + j2 + j3 + 1)
                   * factd(j3 + m3) * factd(j3 - m3)
                   / (factd(j1 - m1) * factd(j1 + m1) * factd(j2 - m2) * factd(j2 + m2)));
  double s = 0.0;
  for (int v = vmin; v <= vmax; ++v) {
    double sgn = ((v + j2 + m2) & 1) ? -1.0 : 1.0;
    s += sgn * factd(j2 + j3 + m1 - v) * factd(j1 - m1 + v)
         / (factd(v) * factd(j3 - j1 + j2 - v) * factd(j3 + m3 - v) * factd(v + j1 - j2 - m3));
  }
  return cc * s;
}

struct C2 { double re, im; };

__device__ C2 qent(int l, int r, int c) {
  double re = 0.0, im = 0.0;
  const double is2 = 0.70710678118654752440;
  int m = r - l;
  if (m < 0) {
    if (c == l - m) re = is2;
    else if (c == l + m) im = -is2;
  } else if (m == 0) {
    if (c == l) re = 1.0;
  } else {
    double sgn = (m & 1) ? -1.0 : 1.0;
    if (c == l + m) re = sgn * is2;
    else if (c == l - m) im = sgn * is2;
  }
  const double pr[4] = {1.0, 0.0, -1.0, 0.0};
  const double pi[4] = {0.0, -1.0, 0.0, 1.0};
  double a = pr[l & 3], bb = pi[l & 3];
  C2 o; o.re = re * a - im * bb; o.im = re * bb + im * a; return o;
}

// Writes cg2 (f16) z-major padded layout: cg2[(CG2OFF4[t] + z*stride4)*4 + mj*nl + ml]
__global__ void cg_init_kernel(__half* __restrict__ cg2) {
  __shared__ double su2_tab[49];
  const int t = blockIdx.x;
  const int j = T_j[t], l = T_l[t], J = T_Jv[t];
  if (j == 0 || l == 0) return;   // copy terms need no cg
  const int nj = 2*j + 1, nl = 2*l + 1, nJ = 2*J + 1;
  const int njnl = nj * nl, stride4 = (njnl + 3) >> 2;
  for (int ik = threadIdx.x; ik < njnl; ik += blockDim.x) {
    int i = ik / nl, k = ik - (ik / nl) * nl;
    int m = (i - j) + (k - l) + J;
    su2_tab[ik] = (m >= 0 && m <= 2*J) ? su2_cg(j, i - j, l, k - l, J, m - J) : 0.0;
  }
  __syncthreads();
  const int n = nJ * njnl;
  for (int e = threadIdx.x; e < n; e += blockDim.x) {
    const int z = e / njnl, rr = e - (e / njnl) * njnl;
    const int mj = rr / nl, ml = rr - (rr / nl) * nl;
    double acc = 0.0;
    for (int i = 0; i < nj; ++i) {
      for (int k = 0; k < nl; ++k) {
        int m = (i - j) + (k - l) + J;
        if (m < 0 || m > 2*J) continue;
        double s2 = su2_tab[i * nl + k];
        if (s2 == 0.0) continue;
        C2 qa = qent(j, i, mj), qb = qent(l, k, ml), qc = qent(J, m, z);
        double r1 = qa.re * qb.re - qa.im * qb.im;
        double i1 = qa.re * qb.im + qa.im * qb.re;
        acc += (r1 * qc.re + i1 * qc.im) * s2;
      }
    }
    cg2[(CG2OFF4[t] + z * stride4) * 4 + rr] = __float2half((float)acc);
  }
}

// Descriptor: d.x = out offset (bv/cb-independent); d.y = ybase4 | cg2b4<<11 | J<<21 | valid<<31
__global__ void desc_init_kernel(uint2* __restrict__ desc) {
  const int t = blockIdx.x;
  const int j = T_j[t], l = T_l[t], J = T_Jv[t];
  const int n = (2*J + 1) * 6;
  const int slot0 = TERM_SLOT[t];
  const bool cp = (j == 0 || l == 0);
  const int nl = 2*l + 1, njnl = (2*j + 1) * nl;
  const int stride4 = (njnl + 3) >> 2;
  for (int i = threadIdx.x; i < n; i += blockDim.x) {
    const int z = i / 6, r = i - (i / 6) * 6;
    const int s = r >> 1, ch4 = r & 1;
    const unsigned ob = (unsigned)(OUT_BASE[J] + T_col[t] * 96 + s * 32 + ch4 * 4 + z * OUT_W[J]);
    int ybase;
    if (!cp)         ybase = (j*j*3 + s) * PITCH + l*l*8 + ch4*4;
    else if (l == 0) ybase = ((j*j + z)*3 + s) * PITCH + ch4*4;
    else             ybase = s * PITCH + (l*l + z)*8 + ch4*4;
    const unsigned cgb4 = (unsigned)(CG2OFF4[t] + z * stride4);
    desc[slot0 + i] = make_uint2(ob,
        (unsigned)(ybase >> 2) | (cgb4 << 11) | ((unsigned)J << 21) | 0x80000000u);
  }
}

// bf16 bits of x (RNE)
__device__ __forceinline__ unsigned bfb(float x) {
  union { __hip_bfloat16 h; unsigned short u; } c;
  c.h = __float2bfloat16(x);
  return (unsigned)c.u;
}

// ---------------- kern pre-transpose: kern[bv][p][y] f32 -> kbf[bv][y][p] bf16 ----------------
__global__ void kern_tr_kernel(const float* __restrict__ kern, short* __restrict__ kbf) {
  const size_t n = KBF_ELEMS;
  for (size_t e = (size_t)blockIdx.x * blockDim.x + threadIdx.x; e < n;
       e += (size_t)gridDim.x * blockDim.x) {
    const size_t bv = e / (NPATCH * NY);
    const int r = (int)(e - bv * (NPATCH * NY));
    const int p = r / NY, y = r - p * NY;
    kbf[bv * (NPATCH * NY) + (size_t)y * NPATCH + p] = (short)bfb(kern[e]);
  }
}

// ---------------- phase-2 fully-unrolled pair body (cg in f16) ----------------
template<int JT, int LT>
__device__ __forceinline__ float4 pairc(const float4* __restrict__ yb4,
                                        const __half* __restrict__ cgp) {
  constexpr int nl = 2*LT + 1, njnl = (2*JT + 1) * nl;
  float a0 = 0.f, a1 = 0.f, a2 = 0.f, a3 = 0.f;
  #pragma unroll
  for (int e = 0; e < njnl; ++e) {
    const int mj = e / nl, ml = e - (e / nl) * nl;   // compile-time
    const float4 yq = yb4[mj * 102 + ml * 2];         // imm offsets (3*PITCH/4 = 102)
    const float c = __half2float(cgp[e]);
    a0 = fmaf(c, yq.x, a0); a1 = fmaf(c, yq.y, a1);
    a2 = fmaf(c, yq.z, a2); a3 = fmaf(c, yq.w, a3);
  }
  float4 o; o.x = a0; o.y = a1; o.z = a2; o.w = a3; return o;
}

// ---------------- phase-2 driver (shared by both variants) ----------------
__device__ __forceinline__ void phase2_all(const float* __restrict__ y_lds,
                                           const __half* __restrict__ cg_lds,
                                           const uint2* __restrict__ desc,
                                           float* __restrict__ out,
                                           int widu, int lane, int bv, int cb) {
  const float4* yall = (const float4*)y_lds;
  #pragma unroll 1
  for (int ri = 0; ri < 3; ++ri) {
    const int rnd = WAVE_RNDS[widu][ri];
    if (rnd < 0) break;
    const uint2 d = desc[(rnd << 6) | lane];
    const unsigned w1 = d.y;
    const float4* yb4 = yall + (w1 & 0x7FF);
    const __half* cgp = cg_lds + (((w1 >> 11) & 0x3FF) << 2);
    const int J = (w1 >> 21) & 3;
    float4 o;
    switch (RND_CLASS[rnd]) {   // wave-uniform (scalar) switch
      case 0: o = pairc<3,3>(yb4, cgp); break;
      case 1: o = pairc<2,3>(yb4, cgp); break;
      case 2: o = pairc<3,2>(yb4, cgp); break;
      case 3: o = pairc<2,2>(yb4, cgp); break;
      case 4: o = pairc<1,3>(yb4, cgp); break;
      case 5: o = pairc<3,1>(yb4, cgp); break;
      case 6: o = pairc<1,2>(yb4, cgp); break;
      case 7: o = pairc<2,1>(yb4, cgp); break;
      case 8: o = pairc<1,1>(yb4, cgp); break;
      default: o = yb4[0]; break;         // copy class
    }
    if (w1 >> 31)
      *(float4*)&out[(size_t)d.x + (size_t)bv * NJW_C[J] + cb * 8] = o;
  }
}

// ---------------- main fused kernel, transposed-bf16-kern variant ----------------
__global__ __launch_bounds__(512, 8) void sh_conv_kernel(
    const float* __restrict__ f0, const float* __restrict__ f1,
    const float* __restrict__ f2, const float* __restrict__ f3,
    const short* __restrict__ kbf, const int* __restrict__ pidx,
    const __half* __restrict__ cg2, const uint2* __restrict__ desc,
    float* __restrict__ out) {
  __shared__ float y_lds[NY * PITCH];   // 26.1 KB
  __shared__ __half cg_lds[NCG2];       // 7.0 KB   (total 33.2 KB)
  const int tid = threadIdx.x;
  const int lane = tid & 63, wid = tid >> 6;
  const int g = lane >> 4, lr = lane & 15;
  const int xcd  = blockIdx.x & 7;
  const int slot = blockIdx.x >> 3;
  const int bv   = ((slot >> 2) << 3) | xcd;   // 0..4095
  const int cb   = slot & 3;                   // channel group: ch in [cb*8, cb*8+8)
  const int b    = bv >> 11;

  // ---- phase 1 (MFMA): issue ALL global loads first, stage cg while they fly
  const int* ip = pidx + (size_t)bv * NPATCH;
  int idx8[8];
  #pragma unroll
  for (int r = 0; r < 8; ++r) idx8[r] = ip[g * 8 + r];

  // A-frags: one dwordx4 each — kbf[bv][y = m*16+lr][p = g*8 .. g*8+7] (pre-packed bf16)
  const short* kB = kbf + (size_t)bv * (NPATCH * NY);
  short8 afr[3];
  #pragma unroll
  for (int m = 0; m < 3; ++m)
    afr[m] = *(const short8*)(kB + (m*16 + lr) * NPATCH + g * 8);

  // B gather (depends on idx8)
  const int li  = wid * 2 + (lr >> 3);
  const int chl = lr & 7;
  const int l_  = LI_L[li], mlv = LI_ML[li], wq = LI_WQ[li];
  const float* fp = (l_ == 0) ? f0 : (l_ == 1) ? f1 : (l_ == 2) ? f2 : f3;
  const float* base = fp + ((size_t)b * NSRC) * (wq * 32) + mlv * 32 + cb * 8 + chl;
  float bv8[8];
  #pragma unroll
  for (int r = 0; r < 8; ++r) bv8[r] = base[(size_t)(idx8[r] * wq) << 5];

  // cg staging overlaps the in-flight gathers
  {
    const unsigned* cgu = (const unsigned*)cg2;
    unsigned* cglu = (unsigned*)cg_lds;
    for (int i = tid; i < NCG2 / 2; i += 512) cglu[i] = cgu[i];
  }

  short8 bfr;
  #pragma unroll
  for (int r = 0; r < 8; ++r) bfr[r] = (short)bfb(bv8[r]);

  f32x4 acc0 = {0.f,0.f,0.f,0.f}, acc1 = {0.f,0.f,0.f,0.f}, acc2 = {0.f,0.f,0.f,0.f};
  acc0 = __builtin_amdgcn_mfma_f32_16x16x32_bf16(afr[0], bfr, acc0, 0, 0, 0);
  acc1 = __builtin_amdgcn_mfma_f32_16x16x32_bf16(afr[1], bfr, acc1, 0, 0, 0);
  acc2 = __builtin_amdgcn_mfma_f32_16x16x32_bf16(afr[2], bfr, acc2, 0, 0, 0);

  // D: col(n)=lane&15, row(m)=g*4+q -> y_lds[(m*16+g*4+q)][wid*16+lr]
  #pragma unroll
  for (int q = 0; q < 4; ++q) {
    y_lds[(0*16 + g*4 + q) * PITCH + wid*16 + lr] = acc0[q];
    y_lds[(1*16 + g*4 + q) * PITCH + wid*16 + lr] = acc1[q];
    y_lds[(2*16 + g*4 + q) * PITCH + wid*16 + lr] = acc2[q];
  }

  __syncthreads();

  const int widu = __builtin_amdgcn_readfirstlane(wid);
  phase2_all(y_lds, cg_lds, desc, out, widu, lane, bv, cb);
}

// ---------------- fallback variant (exact r11 phase 1: scalar f32 kern loads) ----------------
__global__ __launch_bounds__(512, 8) void sh_conv_kernel_fb(
    const float* __restrict__ f0, const float* __restrict__ f1,
    const float* __restrict__ f2, const float* __restrict__ f3,
    const float* __restrict__ kern, const int* __restrict__ pidx,
    const __half* __restrict__ cg2, const uint2* __restrict__ desc,
    float* __restrict__ out) {
  __shared__ float y_lds[NY * PITCH];
  __shared__ __half cg_lds[NCG2];
  const int tid = threadIdx.x;
  const int lane = tid & 63, wid = tid >> 6;
  const int g = lane >> 4, lr = lane & 15;
  const int xcd  = blockIdx.x & 7;
  const int slot = blockIdx.x >> 3;
  const int bv   = ((slot >> 2) << 3) | xcd;
  const int cb   = slot & 3;
  const int b    = bv >> 11;

  const int* ip = pidx + (size_t)bv * NPATCH;
  int idx8[8];
  #pragma unroll
  for (int r = 0; r < 8; ++r) idx8[r] = ip[g * 8 + r];

  const float* kB = kern + (size_t)bv * (NPATCH * NY);
  float afv[3][8];
  #pragma unroll
  for (int m = 0; m < 3; ++m)
    #pragma unroll
    for (int r = 0; r < 8; ++r)
      afv[m][r] = kB[(g*8 + r) * NY + m*16 + lr];

  const int li  = wid * 2 + (lr >> 3);
  const int chl = lr & 7;
  const int l_  = LI_L[li], mlv = LI_ML[li], wq = LI_WQ[li];
  const float* fp = (l_ == 0) ? f0 : (l_ == 1) ? f1 : (l_ == 2) ? f2 : f3;
  const float* base = fp + ((size_t)b * NSRC) * (wq * 32) + mlv * 32 + cb * 8 + chl;
  float bv8[8];
  #pragma unroll
  for (int r = 0; r < 8; ++r) bv8[r] = base[(size_t)(idx8[r] * wq) << 5];

  {
    const unsigned* cgu = (const unsigned*)cg2;
    unsigned* cglu = (unsigned*)cg_lds;
    for (int i = tid; i < NCG2 / 2; i += 512) cglu[i] = cgu[i];
  }

  short8 afr[3];
  #pragma unroll
  for (int m = 0; m < 3; ++m) {
    short8 af;
    #pragma unroll
    for (int r = 0; r < 8; ++r) af[r] = (short)bfb(afv[m][r]);
    afr[m] = af;
  }
  short8 bfr;
  #pragma unroll
  for (int r = 0; r < 8; ++r) bfr[r] = (short)bfb(bv8[r]);

  f32x4 acc0 = {0.f,0.f,0.f,0.f}, acc1 = {0.f,0.f,0.f,0.f}, acc2 = {0.f,0.f,0.f,0.f};
  acc0 = __builtin_amdgcn_mfma_f32_16x16x32_bf16(afr[0], bfr, acc0, 0, 0, 0);
  acc1 = __builtin_amdgcn_mfma_f32_16x16x32_bf16(afr[1], bfr, acc1, 0, 0, 0);
  acc2 = __builtin_amdgcn_mfma_f32_16x16x32_bf16(afr[2], bfr, acc2, 0, 0, 0);

  #pragma unroll
  for (int q = 0; q < 4; ++q) {
    y_lds[(0*16 + g*4 + q) * PITCH + wid*16 + lr] = acc0[q];
    y_lds[(1*16 + g*4 + q) * PITCH + wid*16 + lr] = acc1[q];
    y_lds[(2*16 + g*4 + q) * PITCH + wid*16 + lr] = acc2[q];
  }

  __syncthreads();

  const int widu = __builtin_amdgcn_readfirstlane(wid);
  phase2_all(y_lds, cg_lds, desc, out, widu, lane, bv, cb);
}

extern "C" void kernel_launch(void* const* d_in, const int* in_sizes, int n_in,
                              void* d_out, int out_size, void* d_ws, size_t ws_size,
                              hipStream_t stream) {
  const float* f0   = (const float*)d_in[0];
  const float* f1   = (const float*)d_in[1];
  const float* f2   = (const float*)d_in[2];
  const float* f3   = (const float*)d_in[3];
  const float* kern = (const float*)d_in[4];
  const int*   pidx = (const int*)d_in[5];
  float* out  = (float*)d_out;
  __half* cg2 = (__half*)d_ws;
  uint2* desc = (uint2*)((char*)d_ws + DESC_OFF);
  short* kbf  = (short*)((char*)d_ws + KBF_OFF);

  hipMemsetAsync(desc, 0, NSLOTS * sizeof(uint2), stream);   // invalid-fill pad slots
  hipLaunchKernelGGL(cg_init_kernel, dim3(NTERMS), dim3(256), 0, stream, cg2);
  hipLaunchKernelGGL(desc_init_kernel, dim3(NTERMS), dim3(64), 0, stream, desc);

  const bool use_kbf = ws_size >= (size_t)KBF_OFF + KBF_ELEMS * sizeof(short);
  if (use_kbf) {
    hipLaunchKernelGGL(kern_tr_kernel, dim3(2048), dim3(256), 0, stream, kern, kbf);
    hipLaunchKernelGGL(sh_conv_kernel, dim3(4 * 2 * NTGT), dim3(512), 0, stream,
                       f0, f1, f2, f3, kbf, pidx, cg2, desc, out);
  } else {
    hipLaunchKernelGGL(sh_conv_kernel_fb, dim3(4 * 2 * NTGT), dim3(512), 0, stream,
                       f0, f1, f2, f3, kern, pidx, cg2, desc, out);
  }
}

// Round 16
// 197.368 us; speedup vs baseline: 1.1378x; 1.1378x over previous
//
#include <hip/hip_runtime.h>
#include <hip/hip_bf16.h>
#include <hip/hip_fp16.h>

#define NTGT 2048
#define NSRC 4096
#define NPATCH 32
#define NY 48
#define PITCH 136          // 136 mod 16 == 8 -> s-streams hit disjoint bank windows
#define NCG2 3524          // padded z-major cg table (halves)
#define NSLOTS 1280        // 20 rounds x 64
#define DESC_OFF 16384     // byte offset of descriptor table in d_ws
#define KBF_OFF 32768      // byte offset of transposed bf16 kern in d_ws
#define KBF_ELEMS ((size_t)4096 * NY * NPATCH)   // 6.29M bf16 = 12.58 MB

using short8 = __attribute__((ext_vector_type(8))) short;
using f32x4  = __attribute__((ext_vector_type(4))) float;

#define NTERMS 34
// term tables: order matches reference out[J] concatenation order (r2-proven)
__constant__ int T_j[NTERMS]    = {0,1,2,3, 1,0,1,2,1,2,3,2,3, 2,0,1,2,3,1,2,3,1,2,3, 3,0,2,3,1,2,3,1,2,3};
__constant__ int T_l[NTERMS]    = {0,1,2,3, 0,1,1,1,2,2,2,3,3, 0,2,1,1,1,2,2,2,3,3,3, 0,3,1,1,2,2,2,3,3,3};
__constant__ int T_Jv[NTERMS]   = {0,0,0,0, 1,1,1,1,1,1,1,1,1, 2,2,2,2,2,2,2,2,2,2,2, 3,3,3,3,3,3,3,3,3,3};
__constant__ int T_col[NTERMS]  = {0,1,2,3, 0,1,2,3,4,5,6,7,8, 0,1,2,3,4,5,6,7,8,9,10, 0,1,2,3,4,5,6,7,8,9};
__constant__ int OUT_BASE[4] = {0, 1572864, 12189696, 33816576};
__constant__ int OUT_W[4]    = {384, 864, 1056, 960};
__constant__ int NJW_C[4]    = {384, 2592, 5280, 6720};   // (2J+1)*W
// n-tile li -> (l, ml, row-width/32) for phase-1 B gather
__constant__ int LI_L[16]  = {0,1,1,1,2,2,2,2,2,3,3,3,3,3,3,3};
__constant__ int LI_ML[16] = {0,0,1,2,0,1,2,3,4,0,1,2,3,4,5,6};
__constant__ int LI_WQ[16] = {1,3,3,3,5,5,5,5,5,7,7,7,7,7,7,7};
// phase-2 schedule: desc slot base per term (class-pure 64-slot rounds)
__constant__ int TERM_SLOT[NTERMS] = {1088,1024,384,0, 1094,1184,1030,896,768,390,256,128,6,
                                      1112,1202,1048,914,640,786,408,274,512,146,24,
                                      1142,1232,944,670,816,438,304,542,176,54};
// cg2 base offset (float4-unit indexing) per term (0 for copy terms)
__constant__ int CG2OFF4[NTERMS] = {0,0,3,10, 0,0,23,32,44,56,77,104,131,
                                    0,0,170,185,205,235,255,290,335,365,410,
                                    0,0,475,503,545,573,622,685,727,790};
// round -> class: 0:(3,3) 1:(2,3) 2:(3,2) 3:(2,2) 4:(1,3) 5:(3,1) 6:(1,2) 7:(2,1) 8:(1,1) 9:copy
__constant__ int RND_CLASS[20] = {0,0,1,1,2,2,3,3,4,4,5,5,6,6,7,7,8,9,9,9};
// wave -> its rounds (balanced: max 58 iter-units vs avg 56)
__constant__ signed char WAVE_RNDS[8][3] = {
  {0,17,-1},{1,16,-1},{2,8,-1},{3,9,18},{4,10,19},{5,11,-1},{6,14,13},{7,15,12}};

// ---------------- CG math (device, double precision) ----------------
__device__ double factd(int n) { double r = 1.0; for (int i = 2; i <= n; ++i) r *= i; return r; }

__device__ double su2_cg(int j1, int m1, int j2, int m2, int j3, int m3) {
  if (m3 != m1 + m2) return 0.0;
  int vmin = max(max(-j1 + j2 + m3, -j1 + m1), 0);
  int vmax = min(min(j2 + j3 + m1, j3 - j1 + j2), j3 + m3);
  double cc = sqrt((2.0*j3 + 1.0) * factd(j3 + j1 - j2) * factd(j3 - j1 + j2) * factd(j1 + j2 - j3)
                   / factd(j1 + j2 + j3 + 1)
                   * factd(j3 + m3) * factd(j3 - m3)
                   / (factd(j1 - m1) * factd(j1 + m1) * factd(j2 - m2) * factd(j2 + m2)));
  double s = 0.0;
  for (int v = vmin; v <= vmax; ++v) {
    double sgn = ((v + j2 + m2) & 1) ? -1.0 : 1.0;
    s += sgn * factd(j2 + j3 + m1 - v) * factd(j1 - m1 + v)
         / (factd(v) * factd(j3 - j1 + j2 - v) * factd(j3 + m3 - v) * factd(v + j1 - j2 - m3));
  }
  return cc * s;
}

struct C2 { double re, im; };

__device__ C2 qent(int l, int r, int c) {
  double re = 0.0, im = 0.0;
  const double is2 = 0.70710678118654752440;
  int m = r - l;
  if (m < 0) {
    if (c == l - m) re = is2;
    else if (c == l + m) im = -is2;
  } else if (m == 0) {
    if (c == l) re = 1.0;
  } else {
    double sgn = (m & 1) ? -1.0 : 1.0;
    if (c == l + m) re = sgn * is2;
    else if (c == l - m) im = sgn * is2;
  }
  const double pr[4] = {1.0, 0.0, -1.0, 0.0};
  const double pi[4] = {0.0, -1.0, 0.0, 1.0};
  double a = pr[l & 3], bb = pi[l & 3];
  C2 o; o.re = re * a - im * bb; o.im = re * bb + im * a; return o;
}

// Writes cg2 (f16) z-major padded layout: cg2[(CG2OFF4[t] + z*stride4)*4 + mj*nl + ml]
__global__ void cg_init_kernel(__half* __restrict__ cg2) {
  __shared__ double su2_tab[49];
  const int t = blockIdx.x;
  const int j = T_j[t], l = T_l[t], J = T_Jv[t];
  if (j == 0 || l == 0) return;   // copy terms need no cg
  const int nj = 2*j + 1, nl = 2*l + 1, nJ = 2*J + 1;
  const int njnl = nj * nl, stride4 = (njnl + 3) >> 2;
  for (int ik = threadIdx.x; ik < njnl; ik += blockDim.x) {
    int i = ik / nl, k = ik - (ik / nl) * nl;
    int m = (i - j) + (k - l) + J;
    su2_tab[ik] = (m >= 0 && m <= 2*J) ? su2_cg(j, i - j, l, k - l, J, m - J) : 0.0;
  }
  __syncthreads();
  const int n = nJ * njnl;
  for (int e = threadIdx.x; e < n; e += blockDim.x) {
    const int z = e / njnl, rr = e - (e / njnl) * njnl;
    const int mj = rr / nl, ml = rr - (rr / nl) * nl;
    double acc = 0.0;
    for (int i = 0; i < nj; ++i) {
      for (int k = 0; k < nl; ++k) {
        int m = (i - j) + (k - l) + J;
        if (m < 0 || m > 2*J) continue;
        double s2 = su2_tab[i * nl + k];
        if (s2 == 0.0) continue;
        C2 qa = qent(j, i, mj), qb = qent(l, k, ml), qc = qent(J, m, z);
        double r1 = qa.re * qb.re - qa.im * qb.im;
        double i1 = qa.re * qb.im + qa.im * qb.re;
        acc += (r1 * qc.re + i1 * qc.im) * s2;
      }
    }
    cg2[(CG2OFF4[t] + z * stride4) * 4 + rr] = __float2half((float)acc);
  }
}

// Descriptor: d.x = out offset (bv/cb-independent); d.y = ybase4 | cg2b4<<11 | J<<21 | valid<<31
__global__ void desc_init_kernel(uint2* __restrict__ desc) {
  const int t = blockIdx.x;
  const int j = T_j[t], l = T_l[t], J = T_Jv[t];
  const int n = (2*J + 1) * 6;
  const int slot0 = TERM_SLOT[t];
  const bool cp = (j == 0 || l == 0);
  const int nl = 2*l + 1, njnl = (2*j + 1) * nl;
  const int stride4 = (njnl + 3) >> 2;
  for (int i = threadIdx.x; i < n; i += blockDim.x) {
    const int z = i / 6, r = i - (i / 6) * 6;
    const int s = r >> 1, ch4 = r & 1;
    const unsigned ob = (unsigned)(OUT_BASE[J] + T_col[t] * 96 + s * 32 + ch4 * 4 + z * OUT_W[J]);
    int ybase;
    if (!cp)         ybase = (j*j*3 + s) * PITCH + l*l*8 + ch4*4;
    else if (l == 0) ybase = ((j*j + z)*3 + s) * PITCH + ch4*4;
    else             ybase = s * PITCH + (l*l + z)*8 + ch4*4;
    const unsigned cgb4 = (unsigned)(CG2OFF4[t] + z * stride4);
    desc[slot0 + i] = make_uint2(ob,
        (unsigned)(ybase >> 2) | (cgb4 << 11) | ((unsigned)J << 21) | 0x80000000u);
  }
}

// bf16 bits of x (RNE)
__device__ __forceinline__ unsigned bfb(float x) {
  union { __hip_bfloat16 h; unsigned short u; } c;
  c.h = __float2bfloat16(x);
  return (unsigned)c.u;
}

// ---------------- kern pre-transpose, LDS-staged & fully coalesced ----------------
// kern[bv][p][y] f32 -> kbf[bv][y][p] bf16. One block per bv.
// Reads: 1536 f32 coalesced. LDS tile padded to pitch 33 (no systematic conflicts).
// Writes: 768 dwords contiguous per bv.
#define KTP 33
__global__ __launch_bounds__(256) void kern_tr_kernel(const float* __restrict__ kern,
                                                      short* __restrict__ kbf) {
  __shared__ short tile[NY * KTP];   // 48 x 33 shorts = 3.2 KB
  const size_t bv = blockIdx.x;
  const float* src = kern + bv * (NPATCH * NY);
  #pragma unroll
  for (int q = 0; q < 6; ++q) {
    const int e = q * 256 + threadIdx.x;        // e = p*48 + y
    const int p = e / NY, y = e - p * NY;
    tile[y * KTP + p] = (short)bfb(src[e]);
  }
  __syncthreads();
  unsigned* dst = (unsigned*)(kbf + bv * (NPATCH * NY));
  #pragma unroll
  for (int q = 0; q < 3; ++q) {
    const int i = q * 256 + threadIdx.x;        // dword i = shorts (2i, 2i+1)
    const int y = i >> 4, p = (i & 15) * 2;     // 16 dwords per y-row
    const unsigned lo = (unsigned)(unsigned short)tile[y * KTP + p];
    const unsigned hi = (unsigned)(unsigned short)tile[y * KTP + p + 1];
    dst[i] = lo | (hi << 16);
  }
}

// ---------------- phase-2 fully-unrolled pair body (cg in f16) ----------------
template<int JT, int LT>
__device__ __forceinline__ float4 pairc(const float4* __restrict__ yb4,
                                        const __half* __restrict__ cgp) {
  constexpr int nl = 2*LT + 1, njnl = (2*JT + 1) * nl;
  float a0 = 0.f, a1 = 0.f, a2 = 0.f, a3 = 0.f;
  #pragma unroll
  for (int e = 0; e < njnl; ++e) {
    const int mj = e / nl, ml = e - (e / nl) * nl;   // compile-time
    const float4 yq = yb4[mj * 102 + ml * 2];         // imm offsets (3*PITCH/4 = 102)
    const float c = __half2float(cgp[e]);
    a0 = fmaf(c, yq.x, a0); a1 = fmaf(c, yq.y, a1);
    a2 = fmaf(c, yq.z, a2); a3 = fmaf(c, yq.w, a3);
  }
  float4 o; o.x = a0; o.y = a1; o.z = a2; o.w = a3; return o;
}

// ---------------- phase-2 driver (shared by both variants) ----------------
__device__ __forceinline__ void phase2_all(const float* __restrict__ y_lds,
                                           const __half* __restrict__ cg_lds,
                                           const uint2* __restrict__ desc,
                                           float* __restrict__ out,
                                           int widu, int lane, int bv, int cb) {
  const float4* yall = (const float4*)y_lds;
  #pragma unroll 1
  for (int ri = 0; ri < 3; ++ri) {
    const int rnd = WAVE_RNDS[widu][ri];
    if (rnd < 0) break;
    const uint2 d = desc[(rnd << 6) | lane];
    const unsigned w1 = d.y;
    const float4* yb4 = yall + (w1 & 0x7FF);
    const __half* cgp = cg_lds + (((w1 >> 11) & 0x3FF) << 2);
    const int J = (w1 >> 21) & 3;
    float4 o;
    switch (RND_CLASS[rnd]) {   // wave-uniform (scalar) switch
      case 0: o = pairc<3,3>(yb4, cgp); break;
      case 1: o = pairc<2,3>(yb4, cgp); break;
      case 2: o = pairc<3,2>(yb4, cgp); break;
      case 3: o = pairc<2,2>(yb4, cgp); break;
      case 4: o = pairc<1,3>(yb4, cgp); break;
      case 5: o = pairc<3,1>(yb4, cgp); break;
      case 6: o = pairc<1,2>(yb4, cgp); break;
      case 7: o = pairc<2,1>(yb4, cgp); break;
      case 8: o = pairc<1,1>(yb4, cgp); break;
      default: o = yb4[0]; break;         // copy class
    }
    if (w1 >> 31)
      *(float4*)&out[(size_t)d.x + (size_t)bv * NJW_C[J] + cb * 8] = o;
  }
}

// ---------------- main fused kernel, transposed-bf16-kern variant ----------------
__global__ __launch_bounds__(512, 8) void sh_conv_kernel(
    const float* __restrict__ f0, const float* __restrict__ f1,
    const float* __restrict__ f2, const float* __restrict__ f3,
    const short* __restrict__ kbf, const int* __restrict__ pidx,
    const __half* __restrict__ cg2, const uint2* __restrict__ desc,
    float* __restrict__ out) {
  __shared__ float y_lds[NY * PITCH];   // 26.1 KB
  __shared__ __half cg_lds[NCG2];       // 7.0 KB   (total 33.2 KB)
  const int tid = threadIdx.x;
  const int lane = tid & 63, wid = tid >> 6;
  const int g = lane >> 4, lr = lane & 15;
  const int xcd  = blockIdx.x & 7;
  const int slot = blockIdx.x >> 3;
  const int bv   = ((slot >> 2) << 3) | xcd;   // 0..4095
  const int cb   = slot & 3;                   // channel group: ch in [cb*8, cb*8+8)
  const int b    = bv >> 11;

  // ---- phase 1 (MFMA): issue ALL global loads first, stage cg while they fly
  const int* ip = pidx + (size_t)bv * NPATCH;
  int idx8[8];
  #pragma unroll
  for (int r = 0; r < 8; ++r) idx8[r] = ip[g * 8 + r];

  // A-frags: one dwordx4 each — kbf[bv][y = m*16+lr][p = g*8 .. g*8+7] (pre-packed bf16)
  const short* kB = kbf + (size_t)bv * (NPATCH * NY);
  short8 afr[3];
  #pragma unroll
  for (int m = 0; m < 3; ++m)
    afr[m] = *(const short8*)(kB + (m*16 + lr) * NPATCH + g * 8);

  // B gather (depends on idx8)
  const int li  = wid * 2 + (lr >> 3);
  const int chl = lr & 7;
  const int l_  = LI_L[li], mlv = LI_ML[li], wq = LI_WQ[li];
  const float* fp = (l_ == 0) ? f0 : (l_ == 1) ? f1 : (l_ == 2) ? f2 : f3;
  const float* base = fp + ((size_t)b * NSRC) * (wq * 32) + mlv * 32 + cb * 8 + chl;
  float bv8[8];
  #pragma unroll
  for (int r = 0; r < 8; ++r) bv8[r] = base[(size_t)(idx8[r] * wq) << 5];

  // cg staging overlaps the in-flight gathers
  {
    const unsigned* cgu = (const unsigned*)cg2;
    unsigned* cglu = (unsigned*)cg_lds;
    for (int i = tid; i < NCG2 / 2; i += 512) cglu[i] = cgu[i];
  }

  short8 bfr;
  #pragma unroll
  for (int r = 0; r < 8; ++r) bfr[r] = (short)bfb(bv8[r]);

  f32x4 acc0 = {0.f,0.f,0.f,0.f}, acc1 = {0.f,0.f,0.f,0.f}, acc2 = {0.f,0.f,0.f,0.f};
  acc0 = __builtin_amdgcn_mfma_f32_16x16x32_bf16(afr[0], bfr, acc0, 0, 0, 0);
  acc1 = __builtin_amdgcn_mfma_f32_16x16x32_bf16(afr[1], bfr, acc1, 0, 0, 0);
  acc2 = __builtin_amdgcn_mfma_f32_16x16x32_bf16(afr[2], bfr, acc2, 0, 0, 0);

  // D: col(n)=lane&15, row(m)=g*4+q -> y_lds[(m*16+g*4+q)][wid*16+lr]
  #pragma unroll
  for (int q = 0; q < 4; ++q) {
    y_lds[(0*16 + g*4 + q) * PITCH + wid*16 + lr] = acc0[q];
    y_lds[(1*16 + g*4 + q) * PITCH + wid*16 + lr] = acc1[q];
    y_lds[(2*16 + g*4 + q) * PITCH + wid*16 + lr] = acc2[q];
  }

  __syncthreads();

  const int widu = __builtin_amdgcn_readfirstlane(wid);
  phase2_all(y_lds, cg_lds, desc, out, widu, lane, bv, cb);
}

// ---------------- fallback variant (exact r11 phase 1: scalar f32 kern loads) ----------------
__global__ __launch_bounds__(512, 8) void sh_conv_kernel_fb(
    const float* __restrict__ f0, const float* __restrict__ f1,
    const float* __restrict__ f2, const float* __restrict__ f3,
    const float* __restrict__ kern, const int* __restrict__ pidx,
    const __half* __restrict__ cg2, const uint2* __restrict__ desc,
    float* __restrict__ out) {
  __shared__ float y_lds[NY * PITCH];
  __shared__ __half cg_lds[NCG2];
  const int tid = threadIdx.x;
  const int lane = tid & 63, wid = tid >> 6;
  const int g = lane >> 4, lr = lane & 15;
  const int xcd  = blockIdx.x & 7;
  const int slot = blockIdx.x >> 3;
  const int bv   = ((slot >> 2) << 3) | xcd;
  const int cb   = slot & 3;
  const int b    = bv >> 11;

  const int* ip = pidx + (size_t)bv * NPATCH;
  int idx8[8];
  #pragma unroll
  for (int r = 0; r < 8; ++r) idx8[r] = ip[g * 8 + r];

  const float* kB = kern + (size_t)bv * (NPATCH * NY);
  float afv[3][8];
  #pragma unroll
  for (int m = 0; m < 3; ++m)
    #pragma unroll
    for (int r = 0; r < 8; ++r)
      afv[m][r] = kB[(g*8 + r) * NY + m*16 + lr];

  const int li  = wid * 2 + (lr >> 3);
  const int chl = lr & 7;
  const int l_  = LI_L[li], mlv = LI_ML[li], wq = LI_WQ[li];
  const float* fp = (l_ == 0) ? f0 : (l_ == 1) ? f1 : (l_ == 2) ? f2 : f3;
  const float* base = fp + ((size_t)b * NSRC) * (wq * 32) + mlv * 32 + cb * 8 + chl;
  float bv8[8];
  #pragma unroll
  for (int r = 0; r < 8; ++r) bv8[r] = base[(size_t)(idx8[r] * wq) << 5];

  {
    const unsigned* cgu = (const unsigned*)cg2;
    unsigned* cglu = (unsigned*)cg_lds;
    for (int i = tid; i < NCG2 / 2; i += 512) cglu[i] = cgu[i];
  }

  short8 afr[3];
  #pragma unroll
  for (int m = 0; m < 3; ++m) {
    short8 af;
    #pragma unroll
    for (int r = 0; r < 8; ++r) af[r] = (short)bfb(afv[m][r]);
    afr[m] = af;
  }
  short8 bfr;
  #pragma unroll
  for (int r = 0; r < 8; ++r) bfr[r] = (short)bfb(bv8[r]);

  f32x4 acc0 = {0.f,0.f,0.f,0.f}, acc1 = {0.f,0.f,0.f,0.f}, acc2 = {0.f,0.f,0.f,0.f};
  acc0 = __builtin_amdgcn_mfma_f32_16x16x32_bf16(afr[0], bfr, acc0, 0, 0, 0);
  acc1 = __builtin_amdgcn_mfma_f32_16x16x32_bf16(afr[1], bfr, acc1, 0, 0, 0);
  acc2 = __builtin_amdgcn_mfma_f32_16x16x32_bf16(afr[2], bfr, acc2, 0, 0, 0);

  #pragma unroll
  for (int q = 0; q < 4; ++q) {
    y_lds[(0*16 + g*4 + q) * PITCH + wid*16 + lr] = acc0[q];
    y_lds[(1*16 + g*4 + q) * PITCH + wid*16 + lr] = acc1[q];
    y_lds[(2*16 + g*4 + q) * PITCH + wid*16 + lr] = acc2[q];
  }

  __syncthreads();

  const int widu = __builtin_amdgcn_readfirstlane(wid);
  phase2_all(y_lds, cg_lds, desc, out, widu, lane, bv, cb);
}

extern "C" void kernel_launch(void* const* d_in, const int* in_sizes, int n_in,
                              void* d_out, int out_size, void* d_ws, size_t ws_size,
                              hipStream_t stream) {
  const float* f0   = (const float*)d_in[0];
  const float* f1   = (const float*)d_in[1];
  const float* f2   = (const float*)d_in[2];
  const float* f3   = (const float*)d_in[3];
  const float* kern = (const float*)d_in[4];
  const int*   pidx = (const int*)d_in[5];
  float* out  = (float*)d_out;
  __half* cg2 = (__half*)d_ws;
  uint2* desc = (uint2*)((char*)d_ws + DESC_OFF);
  short* kbf  = (short*)((char*)d_ws + KBF_OFF);

  hipMemsetAsync(desc, 0, NSLOTS * sizeof(uint2), stream);   // invalid-fill pad slots
  hipLaunchKernelGGL(cg_init_kernel, dim3(NTERMS), dim3(256), 0, stream, cg2);
  hipLaunchKernelGGL(desc_init_kernel, dim3(NTERMS), dim3(64), 0, stream, desc);

  const bool use_kbf = ws_size >= (size_t)KBF_OFF + KBF_ELEMS * sizeof(short);
  if (use_kbf) {
    hipLaunchKernelGGL(kern_tr_kernel, dim3(4096), dim3(256), 0, stream, kern, kbf);
    hipLaunchKernelGGL(sh_conv_kernel, dim3(4 * 2 * NTGT), dim3(512), 0, stream,
                       f0, f1, f2, f3, kbf, pidx, cg2, desc, out);
  } else {
    hipLaunchKernelGGL(sh_conv_kernel_fb, dim3(4 * 2 * NTGT), dim3(512), 0, stream,
                       f0, f1, f2, f3, kern, pidx, cg2, desc, out);
  }
}

// Round 17
// 193.978 us; speedup vs baseline: 1.1576x; 1.0175x over previous
//
#include <hip/hip_runtime.h>
#include <hip/hip_bf16.h>
#include <hip/hip_fp16.h>

#define NTGT 2048
#define NSRC 4096
#define NPATCH 32
#define NY 48
#define PITCH 136          // 136 mod 16 == 8 -> s-streams hit disjoint bank windows
#define KTP2 40            // kern tile pitch in shorts (80 B rows: 16B-aligned b128 reads)
#define NCG2 3524          // padded z-major cg table (halves)
#define NSLOTS 1280        // 20 rounds x 64
#define DESC_OFF 16384     // byte offset of descriptor table in d_ws

using short8 = __attribute__((ext_vector_type(8))) short;
using f32x4  = __attribute__((ext_vector_type(4))) float;

#define NTERMS 34
// term tables: order matches reference out[J] concatenation order (r2-proven)
__constant__ int T_j[NTERMS]    = {0,1,2,3, 1,0,1,2,1,2,3,2,3, 2,0,1,2,3,1,2,3,1,2,3, 3,0,2,3,1,2,3,1,2,3};
__constant__ int T_l[NTERMS]    = {0,1,2,3, 0,1,1,1,2,2,2,3,3, 0,2,1,1,1,2,2,2,3,3,3, 0,3,1,1,2,2,2,3,3,3};
__constant__ int T_Jv[NTERMS]   = {0,0,0,0, 1,1,1,1,1,1,1,1,1, 2,2,2,2,2,2,2,2,2,2,2, 3,3,3,3,3,3,3,3,3,3};
__constant__ int T_col[NTERMS]  = {0,1,2,3, 0,1,2,3,4,5,6,7,8, 0,1,2,3,4,5,6,7,8,9,10, 0,1,2,3,4,5,6,7,8,9};
__constant__ int OUT_BASE[4] = {0, 1572864, 12189696, 33816576};
__constant__ int OUT_W[4]    = {384, 864, 1056, 960};
__constant__ int NJW_C[4]    = {384, 2592, 5280, 6720};   // (2J+1)*W
// n-tile li -> (l, ml, row-width/32) for phase-1 B gather
__constant__ int LI_L[16]  = {0,1,1,1,2,2,2,2,2,3,3,3,3,3,3,3};
__constant__ int LI_ML[16] = {0,0,1,2,0,1,2,3,4,0,1,2,3,4,5,6};
__constant__ int LI_WQ[16] = {1,3,3,3,5,5,5,5,5,7,7,7,7,7,7,7};
// phase-2 schedule: desc slot base per term (class-pure 64-slot rounds)
__constant__ int TERM_SLOT[NTERMS] = {1088,1024,384,0, 1094,1184,1030,896,768,390,256,128,6,
                                      1112,1202,1048,914,640,786,408,274,512,146,24,
                                      1142,1232,944,670,816,438,304,542,176,54};
// cg2 base offset (float4-unit indexing) per term (0 for copy terms)
__constant__ int CG2OFF4[NTERMS] = {0,0,3,10, 0,0,23,32,44,56,77,104,131,
                                    0,0,170,185,205,235,255,290,335,365,410,
                                    0,0,475,503,545,573,622,685,727,790};
// round -> class: 0:(3,3) 1:(2,3) 2:(3,2) 3:(2,2) 4:(1,3) 5:(3,1) 6:(1,2) 7:(2,1) 8:(1,1) 9:copy
__constant__ int RND_CLASS[20] = {0,0,1,1,2,2,3,3,4,4,5,5,6,6,7,7,8,9,9,9};
// wave -> its rounds (balanced: max 58 iter-units vs avg 56)
__constant__ signed char WAVE_RNDS[8][3] = {
  {0,17,-1},{1,16,-1},{2,8,-1},{3,9,18},{4,10,19},{5,11,-1},{6,14,13},{7,15,12}};

// ---------------- CG math (device, double precision) ----------------
__device__ double factd(int n) { double r = 1.0; for (int i = 2; i <= n; ++i) r *= i; return r; }

__device__ double su2_cg(int j1, int m1, int j2, int m2, int j3, int m3) {
  if (m3 != m1 + m2) return 0.0;
  int vmin = max(max(-j1 + j2 + m3, -j1 + m1), 0);
  int vmax = min(min(j2 + j3 + m1, j3 - j1 + j2), j3 + m3);
  double cc = sqrt((2.0*j3 + 1.0) * factd(j3 + j1 - j2) * factd(j3 - j1 + j2) * factd(j1 + j2 - j3)
                   / factd(j1 + j2 + j3 + 1)
                   * factd(j3 + m3) * factd(j3 - m3)
                   / (factd(j1 - m1) * factd(j1 + m1) * factd(j2 - m2) * factd(j2 + m2)));
  double s = 0.0;
  for (int v = vmin; v <= vmax; ++v) {
    double sgn = ((v + j2 + m2) & 1) ? -1.0 : 1.0;
    s += sgn * factd(j2 + j3 + m1 - v) * factd(j1 - m1 + v)
         / (factd(v) * factd(j3 - j1 + j2 - v) * factd(j3 + m3 - v) * factd(v + j1 - j2 - m3));
  }
  return cc * s;
}

struct C2 { double re, im; };

__device__ C2 qent(int l, int r, int c) {
  double re = 0.0, im = 0.0;
  const double is2 = 0.70710678118654752440;
  int m = r - l;
  if (m < 0) {
    if (c == l - m) re = is2;
    else if (c == l + m) im = -is2;
  } else if (m == 0) {
    if (c == l) re = 1.0;
  } else {
    double sgn = (m & 1) ? -1.0 : 1.0;
    if (c == l + m) re = sgn * is2;
    else if (c == l - m) im = sgn * is2;
  }
  const double pr[4] = {1.0, 0.0, -1.0, 0.0};
  const double pi[4] = {0.0, -1.0, 0.0, 1.0};
  double a = pr[l & 3], bb = pi[l & 3];
  C2 o; o.re = re * a - im * bb; o.im = re * bb + im * a; return o;
}

// Writes cg2 (f16) z-major padded layout: cg2[(CG2OFF4[t] + z*stride4)*4 + mj*nl + ml]
__global__ void cg_init_kernel(__half* __restrict__ cg2) {
  __shared__ double su2_tab[49];
  const int t = blockIdx.x;
  const int j = T_j[t], l = T_l[t], J = T_Jv[t];
  if (j == 0 || l == 0) return;   // copy terms need no cg
  const int nj = 2*j + 1, nl = 2*l + 1, nJ = 2*J + 1;
  const int njnl = nj * nl, stride4 = (njnl + 3) >> 2;
  for (int ik = threadIdx.x; ik < njnl; ik += blockDim.x) {
    int i = ik / nl, k = ik - (ik / nl) * nl;
    int m = (i - j) + (k - l) + J;
    su2_tab[ik] = (m >= 0 && m <= 2*J) ? su2_cg(j, i - j, l, k - l, J, m - J) : 0.0;
  }
  __syncthreads();
  const int n = nJ * njnl;
  for (int e = threadIdx.x; e < n; e += blockDim.x) {
    const int z = e / njnl, rr = e - (e / njnl) * njnl;
    const int mj = rr / nl, ml = rr - (rr / nl) * nl;
    double acc = 0.0;
    for (int i = 0; i < nj; ++i) {
      for (int k = 0; k < nl; ++k) {
        int m = (i - j) + (k - l) + J;
        if (m < 0 || m > 2*J) continue;
        double s2 = su2_tab[i * nl + k];
        if (s2 == 0.0) continue;
        C2 qa = qent(j, i, mj), qb = qent(l, k, ml), qc = qent(J, m, z);
        double r1 = qa.re * qb.re - qa.im * qb.im;
        double i1 = qa.re * qb.im + qa.im * qb.re;
        acc += (r1 * qc.re + i1 * qc.im) * s2;
      }
    }
    cg2[(CG2OFF4[t] + z * stride4) * 4 + rr] = __float2half((float)acc);
  }
}

// Descriptor: d.x = out offset (bv/cb-independent); d.y = ybase4 | cg2b4<<11 | J<<21 | valid<<31
__global__ void desc_init_kernel(uint2* __restrict__ desc) {
  const int t = blockIdx.x;
  const int j = T_j[t], l = T_l[t], J = T_Jv[t];
  const int n = (2*J + 1) * 6;
  const int slot0 = TERM_SLOT[t];
  const bool cp = (j == 0 || l == 0);
  const int nl = 2*l + 1, njnl = (2*j + 1) * nl;
  const int stride4 = (njnl + 3) >> 2;
  for (int i = threadIdx.x; i < n; i += blockDim.x) {
    const int z = i / 6, r = i - (i / 6) * 6;
    const int s = r >> 1, ch4 = r & 1;
    const unsigned ob = (unsigned)(OUT_BASE[J] + T_col[t] * 96 + s * 32 + ch4 * 4 + z * OUT_W[J]);
    int ybase;
    if (!cp)         ybase = (j*j*3 + s) * PITCH + l*l*8 + ch4*4;
    else if (l == 0) ybase = ((j*j + z)*3 + s) * PITCH + ch4*4;
    else             ybase = s * PITCH + (l*l + z)*8 + ch4*4;
    const unsigned cgb4 = (unsigned)(CG2OFF4[t] + z * stride4);
    desc[slot0 + i] = make_uint2(ob,
        (unsigned)(ybase >> 2) | (cgb4 << 11) | ((unsigned)J << 21) | 0x80000000u);
  }
}

// bf16 bits of x (RNE)
__device__ __forceinline__ unsigned bfb(float x) {
  union { __hip_bfloat16 h; unsigned short u; } c;
  c.h = __float2bfloat16(x);
  return (unsigned)c.u;
}

// ---------------- phase-2 fully-unrolled pair body (cg in f16) ----------------
template<int JT, int LT>
__device__ __forceinline__ float4 pairc(const float4* __restrict__ yb4,
                                        const __half* __restrict__ cgp) {
  constexpr int nl = 2*LT + 1, njnl = (2*JT + 1) * nl;
  float a0 = 0.f, a1 = 0.f, a2 = 0.f, a3 = 0.f;
  #pragma unroll
  for (int e = 0; e < njnl; ++e) {
    const int mj = e / nl, ml = e - (e / nl) * nl;   // compile-time
    const float4 yq = yb4[mj * 102 + ml * 2];         // imm offsets (3*PITCH/4 = 102)
    const float c = __half2float(cgp[e]);
    a0 = fmaf(c, yq.x, a0); a1 = fmaf(c, yq.y, a1);
    a2 = fmaf(c, yq.z, a2); a3 = fmaf(c, yq.w, a3);
  }
  float4 o; o.x = a0; o.y = a1; o.z = a2; o.w = a3; return o;
}

// ---------------- phase-2 driver ----------------
__device__ __forceinline__ void phase2_all(const float* __restrict__ y_lds,
                                           const __half* __restrict__ cg_lds,
                                           const uint2* __restrict__ desc,
                                           float* __restrict__ out,
                                           int widu, int lane, int bv, int cb) {
  const float4* yall = (const float4*)y_lds;
  #pragma unroll 1
  for (int ri = 0; ri < 3; ++ri) {
    const int rnd = WAVE_RNDS[widu][ri];
    if (rnd < 0) break;
    const uint2 d = desc[(rnd << 6) | lane];
    const unsigned w1 = d.y;
    const float4* yb4 = yall + (w1 & 0x7FF);
    const __half* cgp = cg_lds + (((w1 >> 11) & 0x3FF) << 2);
    const int J = (w1 >> 21) & 3;
    float4 o;
    switch (RND_CLASS[rnd]) {   // wave-uniform (scalar) switch
      case 0: o = pairc<3,3>(yb4, cgp); break;
      case 1: o = pairc<2,3>(yb4, cgp); break;
      case 2: o = pairc<3,2>(yb4, cgp); break;
      case 3: o = pairc<2,2>(yb4, cgp); break;
      case 4: o = pairc<1,3>(yb4, cgp); break;
      case 5: o = pairc<3,1>(yb4, cgp); break;
      case 6: o = pairc<1,2>(yb4, cgp); break;
      case 7: o = pairc<2,1>(yb4, cgp); break;
      case 8: o = pairc<1,1>(yb4, cgp); break;
      default: o = yb4[0]; break;         // copy class
    }
    if (w1 >> 31)
      *(float4*)&out[(size_t)d.x + (size_t)bv * NJW_C[J] + cb * 8] = o;
  }
}

// ---------------- main fused kernel: in-block LDS kern transpose ----------------
__global__ __launch_bounds__(512, 8) void sh_conv_kernel(
    const float* __restrict__ f0, const float* __restrict__ f1,
    const float* __restrict__ f2, const float* __restrict__ f3,
    const float* __restrict__ kern, const int* __restrict__ pidx,
    const __half* __restrict__ cg2, const uint2* __restrict__ desc,
    float* __restrict__ out) {
  __shared__ float y_lds[NY * PITCH];   // 26.1 KB
  __shared__ __half cg_lds[NCG2];       // 7.0 KB
  __shared__ short ktile[NY * KTP2];    // 3.8 KB  (total 37.0 KB -> 4 blocks/CU)
  const int tid = threadIdx.x;
  const int lane = tid & 63, wid = tid >> 6;
  const int g = lane >> 4, lr = lane & 15;
  // r2/r6 grid mapping: 4 channel-blocks of one bv adjacent, same XCD
  const int xcd  = blockIdx.x & 7;
  const int slot = blockIdx.x >> 3;
  const int bv   = ((slot >> 2) << 3) | xcd;   // 0..4095
  const int cb   = slot & 3;                   // channel group: ch in [cb*8, cb*8+8)
  const int b    = bv >> 11;

  // ---- phase 1: issue ALL global loads first; LDS staging covers their flight
  const int* ip = pidx + (size_t)bv * NPATCH;
  int idx8[8];
  #pragma unroll
  for (int r = 0; r < 8; ++r) idx8[r] = ip[g * 8 + r];

  // kern slice: 1536 f32 coalesced (3/thread); transpose to bf16 ktile[y][p]
  const float* kB = kern + (size_t)bv * (NPATCH * NY);
  float kv[3];
  #pragma unroll
  for (int q = 0; q < 3; ++q) kv[q] = kB[q * 512 + tid];

  // B gather (depends on idx8)
  const int li  = wid * 2 + (lr >> 3);
  const int chl = lr & 7;
  const int l_  = LI_L[li], mlv = LI_ML[li], wq = LI_WQ[li];
  const float* fp = (l_ == 0) ? f0 : (l_ == 1) ? f1 : (l_ == 2) ? f2 : f3;
  const float* base = fp + ((size_t)b * NSRC) * (wq * 32) + mlv * 32 + cb * 8 + chl;
  float bv8[8];
  #pragma unroll
  for (int r = 0; r < 8; ++r) bv8[r] = base[(size_t)(idx8[r] * wq) << 5];

  // cg staging overlaps the in-flight gathers
  {
    const unsigned* cgu = (const unsigned*)cg2;
    unsigned* cglu = (unsigned*)cg_lds;
    for (int i = tid; i < NCG2 / 2; i += 512) cglu[i] = cgu[i];
  }

  // ktile writes (kv arrived while gathers were issuing)
  #pragma unroll
  for (int q = 0; q < 3; ++q) {
    const int e = q * 512 + tid;        // e = p*48 + y
    const int p = e / NY, y = e - (e / NY) * NY;
    ktile[y * KTP2 + p] = (short)bfb(kv[q]);
  }

  __syncthreads();   // ktile + cg ready

  // A-frags: one ds_read_b128 each — ktile[y = m*16+lr][p = g*8 .. g*8+7]
  short8 afr[3];
  #pragma unroll
  for (int m = 0; m < 3; ++m)
    afr[m] = *(const short8*)(ktile + (m*16 + lr) * KTP2 + g * 8);

  short8 bfr;
  #pragma unroll
  for (int r = 0; r < 8; ++r) bfr[r] = (short)bfb(bv8[r]);

  f32x4 acc0 = {0.f,0.f,0.f,0.f}, acc1 = {0.f,0.f,0.f,0.f}, acc2 = {0.f,0.f,0.f,0.f};
  acc0 = __builtin_amdgcn_mfma_f32_16x16x32_bf16(afr[0], bfr, acc0, 0, 0, 0);
  acc1 = __builtin_amdgcn_mfma_f32_16x16x32_bf16(afr[1], bfr, acc1, 0, 0, 0);
  acc2 = __builtin_amdgcn_mfma_f32_16x16x32_bf16(afr[2], bfr, acc2, 0, 0, 0);

  // D: col(n)=lane&15, row(m)=g*4+q -> y_lds[(m*16+g*4+q)][wid*16+lr]
  #pragma unroll
  for (int q = 0; q < 4; ++q) {
    y_lds[(0*16 + g*4 + q) * PITCH + wid*16 + lr] = acc0[q];
    y_lds[(1*16 + g*4 + q) * PITCH + wid*16 + lr] = acc1[q];
    y_lds[(2*16 + g*4 + q) * PITCH + wid*16 + lr] = acc2[q];
  }

  __syncthreads();

  const int widu = __builtin_amdgcn_readfirstlane(wid);
  phase2_all(y_lds, cg_lds, desc, out, widu, lane, bv, cb);
}

extern "C" void kernel_launch(void* const* d_in, const int* in_sizes, int n_in,
                              void* d_out, int out_size, void* d_ws, size_t ws_size,
                              hipStream_t stream) {
  const float* f0   = (const float*)d_in[0];
  const float* f1   = (const float*)d_in[1];
  const float* f2   = (const float*)d_in[2];
  const float* f3   = (const float*)d_in[3];
  const float* kern = (const float*)d_in[4];
  const int*   pidx = (const int*)d_in[5];
  float* out  = (float*)d_out;
  __half* cg2 = (__half*)d_ws;
  uint2* desc = (uint2*)((char*)d_ws + DESC_OFF);

  hipMemsetAsync(desc, 0, NSLOTS * sizeof(uint2), stream);   // invalid-fill pad slots
  hipLaunchKernelGGL(cg_init_kernel, dim3(NTERMS), dim3(256), 0, stream, cg2);
  hipLaunchKernelGGL(desc_init_kernel, dim3(NTERMS), dim3(64), 0, stream, desc);
  hipLaunchKernelGGL(sh_conv_kernel, dim3(4 * 2 * NTGT), dim3(512), 0, stream,
                     f0, f1, f2, f3, kern, pidx, cg2, desc, out);
}